// Round 8
// baseline (11.708 us; speedup 1.0000x reference)
//
#include <hip/hip_runtime.h>
#include <math.h>

namespace {

typedef _Float16 f16;
typedef _Float16 f16x8 __attribute__((ext_vector_type(8)));
typedef _Float16 f16x4 __attribute__((ext_vector_type(4)));
typedef float    f32x4 __attribute__((ext_vector_type(4)));

constexpr int D  = 32;
constexpr int H  = 128;
constexpr int S1 = 40;    // f16 stride, K=32 operands: 80B = 20dw, gcd(20,32)=4 -> 2-way (free)
constexpr int S2 = 152;   // f16 stride, K=128 operands: 304B = 76dw, 76%32=12 -> 2-way (free)
constexpr int THREADS = 256;   // 4 waves = 2 pairs
constexpr int BPP = 16;        // batch rows per wave-pair (= MFMA N)
constexpr int BPB = 32;        // batch rows per block

__device__ __forceinline__ float fast_tanh(float z) {
  float e = __expf(2.0f * z);
  return 1.0f - 2.0f * __builtin_amdgcn_rcpf(e + 1.0f);
}

__device__ __forceinline__ f32x4 mfma16(f16x8 a, f16x8 b, f32x4 c) {
  return __builtin_amdgcn_mfma_f32_16x16x32_f16(a, b, c, 0, 0, 0);
}

// R7 (1 wave/SIMD, 40 MFMA/wave serial chain) measured ~12% issue utilization:
// latency-bound. Here each 16-element group is split across a PAIR of waves
// (half = wv&1): Z/M split by hm-range, S/dsdt/G split by output half (om).
// 20 MFMA/wave, 2048 waves = 2/SIMD, 512 blocks = 2/CU. Handoff via LDS +
// 4 block barriers. Batch stays the MFMA N/col dim throughout (m89 layout).
__global__ __launch_bounds__(THREADS, 1) void fpe_mfma2(
    const float* __restrict__ xg, const float* __restrict__ tg,
    const float* __restrict__ betag, const float* __restrict__ W1g,
    const float* __restrict__ b1g, const float* __restrict__ W2g,
    const float* __restrict__ b2g, float* __restrict__ out, int Btot)
{
  __shared__ alignas(16) f16 W1T[H * S1];   // [k][i]: W1^T x-part, A of Z
  __shared__ alignas(16) f16 W2R[H * S1];   // [k][j]: W2,          A of M
  __shared__ alignas(16) f16 W1X[D * S2];   // [i][k]: W1 x-part,   A of G
  __shared__ alignas(16) f16 W2T[D * S2];   // [j][k]: W2^T,        A of S/dsdt
  __shared__ alignas(16) float b1s[H];
  __shared__ alignas(16) float cks[H];      // c_k = sum_j W1[j,k] W2[k,j]
  __shared__ alignas(16) float b2s[D];
  __shared__ alignas(16) f16  w132h[H];     // W1[32,k] (t-row)
  __shared__ alignas(16) f16 hbuf[2][BPP * S2];  // per pair: h, then q (reused)
  __shared__ alignas(16) f16 rbuf[2][BPP * S2];  // per pair: r = g .* W1[32,:]
  __shared__ alignas(16) f16 vbuf[2][BPP * S1];  // per pair: v = 2s + x
  __shared__ float accb[2][2][16];               // per pair, per half: |resid| col-sums

  const int tid = threadIdx.x;

  // ---- stage weights once per block (float4 loads, f16 both orientations)
  for (int n4 = tid; n4 < (D * H) / 4; n4 += THREADS) {
    float4 w = ((const float4*)W1g)[n4];        // W1[i][k..k+3], i<32
    int flat = n4 * 4, i = flat >> 7, k = flat & 127;
    f16x4 w4 = {(f16)w.x, (f16)w.y, (f16)w.z, (f16)w.w};
    W1T[(k + 0) * S1 + i] = w4[0];
    W1T[(k + 1) * S1 + i] = w4[1];
    W1T[(k + 2) * S1 + i] = w4[2];
    W1T[(k + 3) * S1 + i] = w4[3];
    *(f16x4*)&W1X[i * S2 + k] = w4;
  }
  for (int n4 = tid; n4 < (H * D) / 4; n4 += THREADS) {
    float4 w = ((const float4*)W2g)[n4];        // W2[k][j..j+3]
    int flat = n4 * 4, k = flat >> 5, j = flat & 31;
    f16x4 w4 = {(f16)w.x, (f16)w.y, (f16)w.z, (f16)w.w};
    *(f16x4*)&W2R[k * S1 + j] = w4;
    W2T[(j + 0) * S2 + k] = w4[0];
    W2T[(j + 1) * S2 + k] = w4[1];
    W2T[(j + 2) * S2 + k] = w4[2];
    W2T[(j + 3) * S2 + k] = w4[3];
  }
  if (tid < H) { w132h[tid] = (f16)W1g[D * H + tid]; b1s[tid] = b1g[tid]; }
  if (tid < D) b2s[tid] = b2g[tid];
  __syncthreads();

  if (tid < H) {                                 // c_k, vectorized f16x8 reads
    float c = 0.f;
    #pragma unroll
    for (int q = 0; q < 4; ++q) {
      f16x8 a = *(const f16x8*)&W1T[tid * S1 + 8 * q];
      f16x8 b = *(const f16x8*)&W2R[tid * S1 + 8 * q];
      #pragma unroll
      for (int r = 0; r < 8; ++r) c += (float)a[r] * (float)b[r];
    }
    cks[tid] = c;
  }
  __syncthreads();

  const int wv   = tid >> 6;
  const int ln   = tid & 63;
  const int pi   = wv >> 1;        // pair index within block
  const int half = wv & 1;         // which half of the chain this wave owns
  const int col  = ln & 15;        // batch column
  const int g4   = ln >> 4;        // 16-lane group (K-slice / row-quad)
  const int b0   = blockIdx.x * BPB + pi * BPP;
  const int batch = min(b0 + col, Btot - 1);

  f16* hb = hbuf[pi];
  f16* rb = rbuf[pi];
  f16* vb = vbuf[pi];

  // ---- per-element global loads (issue up front)
  const float* xrow = xg + (size_t)batch * D;
  const float4 xk0 = *(const float4*)(xrow + 8 * g4);            // B-frag of X^T
  const float4 xk1 = *(const float4*)(xrow + 8 * g4 + 4);
  const float4 xcv = *(const float4*)(xrow + 16 * half + 4 * g4);// C-layout x slice
  const float tval = tg[batch];
  const float hbeta = 0.5f * betag[batch];

  f16x8 bx;
  bx[0] = (f16)xk0.x; bx[1] = (f16)xk0.y; bx[2] = (f16)xk0.z; bx[3] = (f16)xk0.w;
  bx[4] = (f16)xk1.x; bx[5] = (f16)xk1.y; bx[6] = (f16)xk1.z; bx[7] = (f16)xk1.w;

  // ===== Z (this wave: hm = 4*half .. 4*half+3): h and r -> LDS
  float hC[4][4];
  #pragma unroll
  for (int n = 0; n < 4; ++n) {
    const int hm = 4 * half + n;
    f16x8 a = *(const f16x8*)&W1T[(16 * hm + col) * S1 + 8 * g4];
    f32x4 zero = {0.f, 0.f, 0.f, 0.f};
    f32x4 z = mfma16(a, bx, zero);
    float4 b1v = *(const float4*)&b1s[16 * hm + 4 * g4];
    f16x4 wtv  = *(const f16x4*)&w132h[16 * hm + 4 * g4];
    f16x4 hv, rv;
    #pragma unroll
    for (int r = 0; r < 4; ++r) {
      float zz = z[r] + ((const float*)&b1v)[r] + (float)wtv[r] * tval;
      float hh = fast_tanh(zz);
      hC[n][r] = hh;
      hv[r] = (f16)hh;
      rv[r] = (f16)(fmaf(-hh, hh, 1.0f) * (float)wtv[r]);
    }
    *(f16x4*)&hb[col * S2 + 16 * hm + 4 * g4] = hv;
    *(f16x4*)&rb[col * S2 + 16 * hm + 4 * g4] = rv;
  }
  __syncthreads();

  // ===== S^T / dsdt^T (this wave: om = half), K=128 over both waves' h,r
  f32x4 sT = {0.f, 0.f, 0.f, 0.f}, dT = {0.f, 0.f, 0.f, 0.f};
  #pragma unroll
  for (int ks = 0; ks < 4; ++ks) {
    f16x8 hvf = *(const f16x8*)&hb[col * S2 + 32 * ks + 8 * g4];
    f16x8 rvf = *(const f16x8*)&rb[col * S2 + 32 * ks + 8 * g4];
    f16x8 a   = *(const f16x8*)&W2T[(16 * half + col) * S2 + 32 * ks + 8 * g4];
    sT = mfma16(a, hvf, sT);
    dT = mfma16(a, rvf, dT);
  }
  {  // s += b2 ; v = 2s + x -> vbuf (this wave's j-half)
    float4 b2v = *(const float4*)&b2s[16 * half + 4 * g4];
    f16x4 vv;
    #pragma unroll
    for (int r = 0; r < 4; ++r) {
      sT[r] += ((const float*)&b2v)[r];
      vv[r] = (f16)fmaf(2.0f, sT[r], ((const float*)&xcv)[r]);
    }
    *(f16x4*)&vb[col * S1 + 16 * half + 4 * g4] = vv;
  }
  __syncthreads();

  // ===== M (this wave: hm = 4*half..+3): q = g.*(m - 2c.*h) -> hbuf (h dead)
  {
    f16x8 bv = *(const f16x8*)&vb[col * S1 + 8 * g4];  // full K=32 v
    #pragma unroll
    for (int n = 0; n < 4; ++n) {
      const int hm = 4 * half + n;
      f16x8 a = *(const f16x8*)&W2R[(16 * hm + col) * S1 + 8 * g4];
      f32x4 zero = {0.f, 0.f, 0.f, 0.f};
      f32x4 m = mfma16(a, bv, zero);
      float4 cv = *(const float4*)&cks[16 * hm + 4 * g4];
      f16x4 qv;
      #pragma unroll
      for (int r = 0; r < 4; ++r) {
        float hh = hC[n][r];
        float mm = fmaf(-2.0f * ((const float*)&cv)[r], hh, m[r]);
        qv[r] = (f16)(fmaf(-hh, hh, 1.0f) * mm);
      }
      *(f16x4*)&hb[col * S2 + 16 * hm + 4 * g4] = qv;
    }
  }
  __syncthreads();

  // ===== G^T (this wave: om = half), K=128 over both waves' q
  f32x4 gT = {0.f, 0.f, 0.f, 0.f};
  #pragma unroll
  for (int ks = 0; ks < 4; ++ks) {
    f16x8 q8 = *(const f16x8*)&hb[col * S2 + 32 * ks + 8 * g4];
    f16x8 a  = *(const f16x8*)&W1X[(16 * half + col) * S2 + 32 * ks + 8 * g4];
    gT = mfma16(a, q8, gT);
  }

  // ===== resid for this wave's 16 j's; L1 partial; combine pair via LDS
  float acc = 0.f;
  #pragma unroll
  for (int r = 0; r < 4; ++r)
    acc += fabsf(dT[r] - hbeta * (sT[r] + gT[r]));
  acc += __shfl_xor(acc, 16);
  acc += __shfl_xor(acc, 32);
  if (ln < 16) accb[pi][half][ln] = acc;
  __syncthreads();
  if (half == 0 && ln < 16) {
    int b = b0 + ln;
    if (b < Btot)
      out[b] = (accb[pi][0][ln] + accb[pi][1][ln]) * (1.0f / 32.0f);
  }
}

} // namespace

extern "C" void kernel_launch(void* const* d_in, const int* in_sizes, int n_in,
                              void* d_out, int out_size, void* d_ws, size_t ws_size,
                              hipStream_t stream) {
  const float* x    = (const float*)d_in[0];
  const float* t    = (const float*)d_in[1];
  const float* beta = (const float*)d_in[2];
  const float* W1   = (const float*)d_in[3];
  const float* b1   = (const float*)d_in[4];
  const float* W2   = (const float*)d_in[5];
  const float* b2   = (const float*)d_in[6];
  float* out = (float*)d_out;

  const int Btot = in_sizes[1];  // t is [B,1]
  const int grid = (Btot + BPB - 1) / BPB;
  hipLaunchKernelGGL(fpe_mfma2, dim3(grid), dim3(THREADS), 0, stream,
                     x, t, beta, W1, b1, W2, b2, out, Btot);
}